// Round 12
// baseline (89.931 us; speedup 1.0000x reference)
//
#include <hip/hip_runtime.h>

#define K      32
#define KH     16                   // bins per lane (pair split)
#define TPB    256
#define NB     2048                 // 2048 blocks * 128 pair-slots * 8 = N
#define EPT    8                    // elements per pair-slot
#define NTOT   (32 * 64 * 1024)     // 2,097,152
#define PSTRIDE (NB * (TPB / 2))    // 262144

__device__ __forceinline__ float wave_reduce_sum(float v) {
#pragma unroll
  for (int m = 1; m < 64; m <<= 1) v += __shfl_xor(v, m, 64);
  return v;
}
// same-parity reduce (masks 2..32), epilogue only
__device__ __forceinline__ float pair_lane_reduce(float v) {
#pragma unroll
  for (int m = 2; m < 64; m <<= 1) v += __shfl_xor(v, m, 64);
  return v;
}
// xor-1 via DPP quad_perm[1,0,3,2] -- VALU pipe, no lgkmcnt
__device__ __forceinline__ float dpp_xor1(float v) {
  return __int_as_float(__builtin_amdgcn_update_dpp(
      0, __float_as_int(v), 0xB1, 0xF, 0xF, true));
}

// R11 insight: 4 structural variants all ~85us => TRANS-PIPE BOUND
// (32 exp2/elem is the invariant; R9's 2x exp2 = +6us confirms).
// Fix: exp2 is monotonic, so t_k = 2^min(u,-u) = min(2^u, 2^-u) with
// u = y - z_k, y = Cf*x, z_k = Cf*b_k. Precompute iz=2^-z, ez=2^z (and
// half-exponent ihz/ehz for the sqrt side) per bin ONCE; per element only
// 4 exp2 (Ey, iEy, Eh, iEh). Per (e,k): 9 VALU, 0 trans. Overflow safe:
// min(inf, tiny)=tiny picks the true side. Pair-split keeps the 5 constant
// arrays (80 regs) VGPR-resident; e-loop 'unroll 1' (only proven-safe).
__global__ __launch_bounds__(TPB)
void ssq_main(const float* __restrict__ x, const float* __restrict__ bins,
              float* __restrict__ out, float* __restrict__ partials) {
  const int tid   = threadIdx.x;
  const int half  = tid & 1;
  const int pslot = blockIdx.x * (TPB / 2) + (tid >> 1);

  const float Cf = -14.426950408889634f;  // ALPHA * log2(e)

  // per-lane bin constants (parity-dependent -> VGPRs)
  float bl[KH], iz[KH], ez[KH], ihz[KH], ehz[KH];
#pragma unroll
  for (int j = 0; j < KH; ++j) {
    float b = bins[KH * half + j];
    float z = Cf * b;
    bl[j]  = b;
    iz[j]  = __builtin_amdgcn_exp2f(-z);
    ez[j]  = __builtin_amdgcn_exp2f(z);
    ihz[j] = __builtin_amdgcn_exp2f(-0.5f * z);
    ehz[j] = __builtin_amdgcn_exp2f(0.5f * z);
  }
  float bs = 0.f;
#pragma unroll
  for (int j = 0; j < KH; ++j) bs += bl[j];
  bs += dpp_xor1(bs);                       // sum over all 32 bins
  const float epsb = 1e-10f * bs;           // eps * sum(bins) term

  float xs[EPT];
#pragma unroll
  for (int e = 0; e < EPT; ++e) xs[e] = x[pslot + e * PSTRIDE];

  float sAcc[KH];
#pragma unroll
  for (int j = 0; j < KH; ++j) sAcc[j] = 0.f;
  float q = 0.f;

#pragma unroll 1
  for (int e = 0; e < EPT; ++e) {
    const float xv = xs[e];
    const float y  = Cf * xv;
    const float Ey  = __builtin_amdgcn_exp2f(y);
    const float iEy = __builtin_amdgcn_exp2f(-y);
    const float Eh  = __builtin_amdgcn_exp2f(0.5f * y);
    const float iEh = __builtin_amdgcn_exp2f(-0.5f * y);
    float t[KH];                            // dies each iteration
    float s0 = 0.f, s1 = 0.f, h0 = 0.f, h1 = 0.f, b0 = 0.f, b1 = 0.f;
#pragma unroll
    for (int j = 0; j < KH; j += 2) {
      float pa = Ey * iz[j + 0], ma = iEy * ez[j + 0];
      float pb = Ey * iz[j + 1], mb = iEy * ez[j + 1];
      float ta = fminf(pa, ma), tb = fminf(pb, mb);   // = 2^(Cf|x-b|)
      t[j + 0] = ta; t[j + 1] = tb;
      s0 += ta; s1 += tb;
      b0 = fmaf(ta, bl[j + 0], b0);
      b1 = fmaf(tb, bl[j + 1], b1);
      float hpa = Eh * ihz[j + 0], hma = iEh * ehz[j + 0];
      float hpb = Eh * ihz[j + 1], hmb = iEh * ehz[j + 1];
      h0 += fminf(hpa, hma);                          // = sqrt(t)
      h1 += fminf(hpb, hmb);
    }
    float s_loc = s0 + s1, b_loc = b0 + b1;
    const float s_full = s_loc + dpp_xor1(s_loc);
    const float b_full = b_loc + dpp_xor1(b_loc);
    const float inv = __builtin_amdgcn_rcpf(s_full);
    q = fmaf(h0 + h1, __builtin_amdgcn_rsqf(s_full), q);
    if (half == 0) out[pslot + e * PSTRIDE] = fmaf(b_full, inv, epsb);
#pragma unroll
    for (int j = 0; j < KH; ++j) sAcc[j] = fmaf(t[j], inv, sAcc[j]);
  }

  // block reduction: same-parity butterfly -> lanes 0/1 hold the two halves
  __shared__ float red[4][K + 1];
  const int lane = tid & 63, wv = tid >> 6;
#pragma unroll
  for (int j = 0; j < KH; ++j) {
    float v = pair_lane_reduce(sAcc[j]);
    if (lane < 2) red[wv][KH * lane + j] = v;
  }
  {
    float v = wave_reduce_sum(q);
    if (lane == 0) red[wv][K] = v;
  }
  __syncthreads();
  if (tid < K + 1) {
    float v = red[0][tid] + red[1][tid] + red[2][tid] + red[3][tid];
    partials[tid * NB + blockIdx.x] = v;    // written exactly once
  }
}

// 33 blocks: block c reduces partials[c*NB .. c*NB+NB) -> sums[c]
__global__ __launch_bounds__(TPB)
void ssq_reduce(const float* __restrict__ partials, float* __restrict__ sums) {
  const float* p = partials + blockIdx.x * NB;
  const int tid  = threadIdx.x;
  float s = 0.f;
#pragma unroll
  for (int j = 0; j < NB / TPB; ++j) s += p[tid + j * TPB];
  s = wave_reduce_sum(s);
  __shared__ float red[4];
  if ((tid & 63) == 0) red[tid >> 6] = s;
  __syncthreads();
  if (tid == 0) sums[blockIdx.x] = red[0] + red[1] + red[2] + red[3];
}

// one wave: entropy over 32 p_k + quant mean + tails
__global__ void ssq_final(const float* __restrict__ sums, float* __restrict__ out) {
  const int lane = threadIdx.x;
  float e = 0.f;
  if (lane < K) {
    float p = sums[lane] * (1.0f / (float)NTOT) + 1e-10f;  // eps folded in
    e = -p * __logf(p);
  }
  e = wave_reduce_sum(e);
  if (lane == 0) {
    out[NTOT + 0] = e;                              // code entropy
    out[NTOT + 1] = 0.f;                            // TAU
    out[NTOT + 2] = sums[K] * (1.0f / (float)NTOT); // quant loss
    out[NTOT + 3] = 0.f;                            // TAU2
  }
}

extern "C" void kernel_launch(void* const* d_in, const int* in_sizes, int n_in,
                              void* d_out, int out_size, void* d_ws, size_t ws_size,
                              hipStream_t stream) {
  const float* x    = (const float*)d_in[0];
  const float* bins = (const float*)d_in[1];
  float* out        = (float*)d_out;
  float* partials   = (float*)d_ws;                 // (K+1)*NB floats = 270 KB
  float* sums       = partials + (K + 1) * NB;      // 33 floats

  ssq_main  <<<NB,    TPB, 0, stream>>>(x, bins, out, partials);
  ssq_reduce<<<K + 1, TPB, 0, stream>>>(partials, sums);
  ssq_final <<<1,     64,  0, stream>>>(sums, out);
}

// Round 13
// 88.660 us; speedup vs baseline: 1.0143x; 1.0143x over previous
//
#include <hip/hip_runtime.h>

#define K      32
#define KQ     8                    // bins per lane (quad split)
#define TPB    256
#define NB     4096                 // 4096 blocks * 64 quad-slots * 8 = N
#define EPT    8                    // elements per quad-slot
#define NTOT   (32 * 64 * 1024)     // 2,097,152
#define PSTRIDE (NB * (TPB / 4))    // 262144

__device__ __forceinline__ float wave_reduce_sum(float v) {
#pragma unroll
  for (int m = 1; m < 64; m <<= 1) v += __shfl_xor(v, m, 64);
  return v;
}
// epilogue-only reduce across the 16 lanes with the same quarter
__device__ __forceinline__ float quarter_reduce(float v) {
#pragma unroll
  for (int m = 4; m < 64; m <<= 1) v += __shfl_xor(v, m, 64);
  return v;
}
// intra-quad xor via DPP quad_perm -- VALU pipe, ~4cyc, no lgkmcnt (R10-proven)
__device__ __forceinline__ float dpp_xor1(float v) {
  return __int_as_float(__builtin_amdgcn_update_dpp(
      0, __float_as_int(v), 0xB1, 0xF, 0xF, true));
}
__device__ __forceinline__ float dpp_xor2(float v) {
  return __int_as_float(__builtin_amdgcn_update_dpp(
      0, __float_as_int(v), 0x4E, 0xF, 0xF, true));
}

// R12 synthesis: R5-R10 share a ~14us trans floor (32 exp2/elem); R11 killed
// the trans but its 5 const arrays (~140 VGPR) killed occupancy — same 24us
// either way. This round takes BOTH: 2-exp2 algebra t=min(Ey*iz, iEy*ez)
// (exp2 monotone; overflow safe: min picks the finite true side) + quad split
// so const arrays are only bl/iz/ez[8] (24 regs). h=sqrt(t) on the now-idle
// trans unit replaces R11's ihz/ehz arrays (-2 arrays, -4 VALU/bin).
// ~7 VALU + 1 trans per (e,k): both pipes ~6-7us, co-issued. Live set ~66
// VGPR -> 7-8 waves/SIMD. e-loop 'unroll 1' (R4=balloon, R7=demotion).
__global__ __launch_bounds__(TPB)
void ssq_main(const float* __restrict__ x, const float* __restrict__ bins,
              float* __restrict__ out, float* __restrict__ partials) {
  const int tid     = threadIdx.x;
  const int quarter = tid & 3;
  const int pslot   = blockIdx.x * (TPB / 4) + (tid >> 2);

  const float Cf = -14.426950408889634f;  // ALPHA * log2(e)

  // per-lane bin constants (parity-dependent -> VGPRs): 3 arrays x 8
  float bl[KQ], iz[KQ], ez[KQ];
#pragma unroll
  for (int j = 0; j < KQ; ++j) {
    float b = bins[KQ * quarter + j];
    float z = Cf * b;
    bl[j] = b;
    iz[j] = __builtin_amdgcn_exp2f(-z);
    ez[j] = __builtin_amdgcn_exp2f(z);
  }
  float bs = 0.f;
#pragma unroll
  for (int j = 0; j < KQ; ++j) bs += bl[j];
  bs += dpp_xor1(bs);
  bs += dpp_xor2(bs);                       // sum over all 32 bins
  const float epsb = 1e-10f * bs;           // eps * sum(bins) term

  float xs[EPT];
#pragma unroll
  for (int e = 0; e < EPT; ++e) xs[e] = x[pslot + e * PSTRIDE];

  float sAcc[KQ];
#pragma unroll
  for (int j = 0; j < KQ; ++j) sAcc[j] = 0.f;
  float q = 0.f;

#pragma unroll 1
  for (int e = 0; e < EPT; ++e) {
    const float xv = xs[e];
    const float y   = Cf * xv;
    const float Ey  = __builtin_amdgcn_exp2f(y);
    const float iEy = __builtin_amdgcn_exp2f(-y);
    float t[KQ];                            // dies each iteration
    float s0 = 0.f, s1 = 0.f, h0 = 0.f, h1 = 0.f, b0 = 0.f, b1 = 0.f;
#pragma unroll
    for (int j = 0; j < KQ; j += 2) {
      float ta = fminf(Ey * iz[j + 0], iEy * ez[j + 0]);   // = 2^(Cf|x-b|)
      float tb = fminf(Ey * iz[j + 1], iEy * ez[j + 1]);
      t[j + 0] = ta; t[j + 1] = tb;
      s0 += ta; s1 += tb;
      b0 = fmaf(ta, bl[j + 0], b0);
      b1 = fmaf(tb, bl[j + 1], b1);
      h0 += __builtin_amdgcn_sqrtf(ta);                    // = sqrt(t), trans pipe
      h1 += __builtin_amdgcn_sqrtf(tb);
    }
    float s_loc = s0 + s1, b_loc = b0 + b1;
    // combine the 4 quarters on the VALU pipe (DPP)
    float s2 = s_loc + dpp_xor1(s_loc);
    float b2 = b_loc + dpp_xor1(b_loc);
    const float s_full = s2 + dpp_xor2(s2);
    const float b_full = b2 + dpp_xor2(b2);
    const float inv = __builtin_amdgcn_rcpf(s_full);
    q = fmaf(h0 + h1, __builtin_amdgcn_rsqf(s_full), q);   // local Σsqrt(a)
    if (quarter == 0) out[pslot + e * PSTRIDE] = fmaf(b_full, inv, epsb);
#pragma unroll
    for (int j = 0; j < KQ; ++j) sAcc[j] = fmaf(t[j], inv, sAcc[j]);
  }

  // block reduction (epilogue): quarter butterfly -> lanes 0-3 write 8 rows
  __shared__ float red[4][K + 1];
  const int lane = tid & 63, wv = tid >> 6;
#pragma unroll
  for (int j = 0; j < KQ; ++j) {
    float v = quarter_reduce(sAcc[j]);
    if (lane < 4) red[wv][KQ * lane + j] = v;
  }
  {
    float v = wave_reduce_sum(q);
    if (lane == 0) red[wv][K] = v;
  }
  __syncthreads();
  if (tid < K + 1) {
    float v = red[0][tid] + red[1][tid] + red[2][tid] + red[3][tid];
    partials[tid * NB + blockIdx.x] = v;    // written exactly once
  }
}

// 33 blocks: block c reduces partials[c*NB .. c*NB+NB) -> sums[c]
__global__ __launch_bounds__(TPB)
void ssq_reduce(const float* __restrict__ partials, float* __restrict__ sums) {
  const float* p = partials + blockIdx.x * NB;
  const int tid  = threadIdx.x;
  float s = 0.f;
#pragma unroll
  for (int j = 0; j < NB / TPB; ++j) s += p[tid + j * TPB];
  s = wave_reduce_sum(s);
  __shared__ float red[4];
  if ((tid & 63) == 0) red[tid >> 6] = s;
  __syncthreads();
  if (tid == 0) sums[blockIdx.x] = red[0] + red[1] + red[2] + red[3];
}

// one wave: entropy over 32 p_k + quant mean + tails
__global__ void ssq_final(const float* __restrict__ sums, float* __restrict__ out) {
  const int lane = threadIdx.x;
  float e = 0.f;
  if (lane < K) {
    float p = sums[lane] * (1.0f / (float)NTOT) + 1e-10f;  // eps folded in
    e = -p * __logf(p);
  }
  e = wave_reduce_sum(e);
  if (lane == 0) {
    out[NTOT + 0] = e;                              // code entropy
    out[NTOT + 1] = 0.f;                            // TAU
    out[NTOT + 2] = sums[K] * (1.0f / (float)NTOT); // quant loss
    out[NTOT + 3] = 0.f;                            // TAU2
  }
}

extern "C" void kernel_launch(void* const* d_in, const int* in_sizes, int n_in,
                              void* d_out, int out_size, void* d_ws, size_t ws_size,
                              hipStream_t stream) {
  const float* x    = (const float*)d_in[0];
  const float* bins = (const float*)d_in[1];
  float* out        = (float*)d_out;
  float* partials   = (float*)d_ws;                 // (K+1)*NB floats = 540 KB
  float* sums       = partials + (K + 1) * NB;      // 33 floats

  ssq_main  <<<NB,    TPB, 0, stream>>>(x, bins, out, partials);
  ssq_reduce<<<K + 1, TPB, 0, stream>>>(partials, sums);
  ssq_final <<<1,     64,  0, stream>>>(sums, out);
}